// Round 1
// baseline (439.016 us; speedup 1.0000x reference)
//
#include <hip/hip_runtime.h>

#define N_NODES 50000
#define N_EDGES 600000
#define DH 128
#define BN_EPS 1e-5f
#define SCAN_BLOCKS ((N_NODES + 255) / 256)   // 196

typedef __attribute__((ext_vector_type(8))) short bf16x8;
typedef __attribute__((ext_vector_type(4))) float f32x4;

// round-to-nearest-even fp32 -> bf16 (bit trick, sign-safe)
__device__ inline unsigned short f2bf(float x) {
  unsigned u = __float_as_uint(x);
  return (unsigned short)((u + 0x7FFFu + ((u >> 16) & 1u)) >> 16);
}
__device__ inline float bf2f(unsigned short h) {
  return __uint_as_float(((unsigned)h) << 16);
}

// async global->LDS, 16 B per lane: lane i's data lands at lds_base + i*16.
__device__ inline void gl_lds16(const unsigned short* g, unsigned short* l) {
  __builtin_amdgcn_global_load_lds(
      (const __attribute__((address_space(1))) unsigned int*)g,
      (__attribute__((address_space(3))) unsigned int*)l, 16, 0, 0);
}

// ---------------------------------------------------------------------------
// Fused weight pre-split (one launch): MFMA B-fragment order
// plane[((kstep32*8 + ctile)*64 + lane)*8 + j], k = kstep32*32 + (lane>>4)*8+j,
// n = ctile*16 + (lane&15). W split hi/lo (Wh+Wl == W to 2^-17) so GEMM error
// is A's bf16 rounding only.
// ---------------------------------------------------------------------------
__global__ __launch_bounds__(256) void convert_W5(
    const float* __restrict__ hW, const float* __restrict__ g1,
    const float* __restrict__ l1, const float* __restrict__ g2,
    const float* __restrict__ l2,
    unsigned short* __restrict__ hH, unsigned short* __restrict__ hL,
    unsigned short* __restrict__ g1H, unsigned short* __restrict__ g1L,
    unsigned short* __restrict__ l1H, unsigned short* __restrict__ l1L,
    unsigned short* __restrict__ g2H, unsigned short* __restrict__ g2L,
    unsigned short* __restrict__ l2H, unsigned short* __restrict__ l2L) {
  int b = blockIdx.x;
  const float* W;
  unsigned short *hi, *lo;
  int idx;
  if (b < 256) {
    W = hW; hi = hH; lo = hL;
    idx = b * 256 + threadIdx.x;
  } else {
    int w = (b - 256) >> 6;
    idx = ((b - 256) & 63) * 256 + threadIdx.x;
    W = (w == 0) ? g1 : (w == 1) ? l1 : (w == 2) ? g2 : l2;
    hi = (w == 0) ? g1H : (w == 1) ? l1H : (w == 2) ? g2H : l2H;
    lo = (w == 0) ? g1L : (w == 1) ? l1L : (w == 2) ? g2L : l2L;
  }
  int k = idx >> 7;
  int n = idx & 127;
  float x = W[idx];
  unsigned short h = f2bf(x);
  unsigned short l = f2bf(x - bf2f(h));
  int kstep = k >> 5;
  int ctile = n >> 4;
  int lane = ((k >> 3) & 3) * 16 + (n & 15);
  int j = k & 7;
  size_t off = ((size_t)(kstep * 8 + ctile) * 64 + lane) * 8 + j;
  hi[off] = h;
  lo[off] = l;
}

// ---------------------------------------------------------------------------
// Coalesced fp32 -> bf16 mirror (separate pass; NEVER fuse scattered ushort
// stores into a GEMM epilogue — R4 showed 10x HBM write amplification).
// ---------------------------------------------------------------------------
__global__ __launch_bounds__(256) void to_bf16(const float* __restrict__ x,
                                               unsigned short* __restrict__ xb) {
  int i = blockIdx.x * 256 + threadIdx.x;
  if (i >= N_NODES * DH / 4) return;
  float4 v = ((const float4*)x)[i];
  ushort4 o;
  o.x = f2bf(v.x); o.y = f2bf(v.y); o.z = f2bf(v.z); o.w = f2bf(v.w);
  ((ushort4*)xb)[i] = o;
}

// ---------------------------------------------------------------------------
// Head GEMM (K=512), pipelined: BK=32, 16 ksteps, ONE raw s_barrier per kstep.
// A (fp32, HBM stream) register-prefetched depth-2; B (L2-resident planes)
// global_load_lds'd depth-1 into a double LDS buffer, issued AFTER the
// barrier so no drain ever touches it. Steady-state wait: s_waitcnt vmcnt(2)
// (the 2 in-flight A loads of kstep ks+1 stay outstanding across the barrier).
// Queue invariant at top of iter ks: [A(ks)(2), B(ks)(4), A(ks+1)(2)];
// vmcnt(2) completes A(ks)+B(ks), preserves A(ks+1). Issue order B-then-A is
// pinned with an asm memory fence (reorder would corrupt the count).
// LDS 43.0 KB -> 3 blocks/CU.
// ---------------------------------------------------------------------------
__global__ __launch_bounds__(256) void gemm_head(const float* __restrict__ A,
                                                 const unsigned short* __restrict__ Bh,
                                                 const unsigned short* __restrict__ Bl,
                                                 const float* __restrict__ bias,
                                                 float* __restrict__ C, int M) {
  constexpr int K = 512;
  constexpr int KSTEPS = K / 32;   // 16
  constexpr int ASTR = 40;         // 32 k + 8 pad
  __shared__ __align__(16) unsigned short Ah[2][64 * ASTR];  // 10.2 KB
  __shared__ __align__(16) unsigned short Bhs[2][4096];      // 16 KB
  __shared__ __align__(16) unsigned short Bls[2][4096];      // 16 KB

  const int tid = threadIdx.x;
  const int wave = tid >> 6;
  const int lane = tid & 63;
  const int m0 = blockIdx.x * 64;

  // A staging: thread owns row tid>>2 (0..63), 8-float group tid&3
  const int s_row = tid >> 2;
  const int s_grp = tid & 3;
  const int g_row = m0 + s_row;
  const int g_rowc = (g_row < M) ? g_row : (M - 1);
  const float* af = A + (size_t)g_rowc * K + s_grp * 8;

  const int rgrp = wave & 1;  // 32-row group
  const int ch = wave >> 1;   // 64-col half

  auto issueB = [&](int ks, int buf) {
    const unsigned short* sh = Bh + (size_t)ks * 4096 + wave * 1024;
    const unsigned short* sl = Bl + (size_t)ks * 4096 + wave * 1024;
    gl_lds16(sh + lane * 8, &Bhs[buf][wave * 1024]);
    gl_lds16(sh + 512 + lane * 8, &Bhs[buf][wave * 1024 + 512]);
    gl_lds16(sl + lane * 8, &Bls[buf][wave * 1024]);
    gl_lds16(sl + 512 + lane * 8, &Bls[buf][wave * 1024 + 512]);
  };

  f32x4 acc[2][4];
#pragma unroll
  for (int r = 0; r < 2; ++r)
#pragma unroll
    for (int c = 0; c < 4; ++c) acc[r][c] = (f32x4){0.f, 0.f, 0.f, 0.f};

  // prologue: A(0), B(0), fence, A(1)  (A(1) must stay youngest in the queue)
  float4 ar[2][2];
  ar[0][0] = *(const float4*)(af + 0);
  ar[0][1] = *(const float4*)(af + 4);
  issueB(0, 0);
  asm volatile("" ::: "memory");
  ar[1][0] = *(const float4*)(af + 32);
  ar[1][1] = *(const float4*)(af + 36);

#pragma unroll
  for (int ks = 0; ks < KSTEPS; ++ks) {
    const int cur = ks & 1;
    if (ks < KSTEPS - 1)
      asm volatile("s_waitcnt vmcnt(2)" ::: "memory");
    else
      asm volatile("s_waitcnt vmcnt(0)" ::: "memory");

    // ---- convert + stage A(ks) into Ah[cur] ----
    {
      float4 f0 = ar[cur][0];
      float4 f1 = ar[cur][1];
      ushort4 h0, h1;
      h0.x = f2bf(f0.x); h0.y = f2bf(f0.y); h0.z = f2bf(f0.z); h0.w = f2bf(f0.w);
      h1.x = f2bf(f1.x); h1.y = f2bf(f1.y); h1.z = f2bf(f1.z); h1.w = f2bf(f1.w);
      int base = s_row * ASTR + s_grp * 8;
      *(ushort4*)&Ah[cur][base + 0] = h0;
      *(ushort4*)&Ah[cur][base + 4] = h1;
    }
    asm volatile("s_waitcnt lgkmcnt(0)" ::: "memory");
    __builtin_amdgcn_s_barrier();

    // ---- issue next tiles (after barrier: nothing drains them) ----
    if (ks + 1 < KSTEPS) issueB(ks + 1, cur ^ 1);
    asm volatile("" ::: "memory");  // pin B-before-A issue order
    if (ks + 2 < KSTEPS) {
      ar[cur][0] = *(const float4*)(af + (ks + 2) * 32);
      ar[cur][1] = *(const float4*)(af + (ks + 2) * 32 + 4);
    }

    // ---- compute kstep ks: 16 MFMA / wave ----
    bf16x8 a0 = *(const bf16x8*)&Ah[cur][(rgrp * 32 + (lane & 15)) * ASTR + (lane >> 4) * 8];
    bf16x8 a1 = *(const bf16x8*)&Ah[cur][(rgrp * 32 + 16 + (lane & 15)) * ASTR + (lane >> 4) * 8];
#pragma unroll
    for (int c = 0; c < 4; ++c) {
      int ct = ch * 4 + c;
      bf16x8 bh = *(const bf16x8*)&Bhs[cur][(ct * 64 + lane) * 8];
      bf16x8 bl = *(const bf16x8*)&Bls[cur][(ct * 64 + lane) * 8];
      acc[0][c] = __builtin_amdgcn_mfma_f32_16x16x32_bf16(a0, bh, acc[0][c], 0, 0, 0);
      acc[0][c] = __builtin_amdgcn_mfma_f32_16x16x32_bf16(a0, bl, acc[0][c], 0, 0, 0);
      acc[1][c] = __builtin_amdgcn_mfma_f32_16x16x32_bf16(a1, bh, acc[1][c], 0, 0, 0);
      acc[1][c] = __builtin_amdgcn_mfma_f32_16x16x32_bf16(a1, bl, acc[1][c], 0, 0, 0);
    }
  }

  // ---- epilogue: C/D layout col=lane&15, row=(lane>>4)*4+reg; relu ----
  const int coln = lane & 15;
  const int rown = (lane >> 4) * 4;
#pragma unroll
  for (int c = 0; c < 4; ++c) {
    int colg = (ch * 4 + c) * 16 + coln;
    float bv = bias[colg];
#pragma unroll
    for (int r = 0; r < 2; ++r) {
#pragma unroll
      for (int reg = 0; reg < 4; ++reg) {
        int row = m0 + rgrp * 32 + r * 16 + rown + reg;
        if (row < M) {
          float v = fmaxf(acc[r][c][reg] + bv, 0.f);
          C[(size_t)row * DH + colg] = v;
        }
      }
    }
  }
}

// ---------------------------------------------------------------------------
// Fused GIN MLP pair, pipelined: X = (relu(y @ W1 + b1)) @ W2 + b2.
// A (64 B/thread total) staged to LDS ONCE in the prologue; the SAME LDS
// buffer is reused for h in stage 2 (A reads all complete before the h-write
// barrier). B double-buffered, global_load_lds issued one kstep ahead after
// each barrier; per-kstep wait is vmcnt(0) which drains exactly the current
// B batch (nothing else is ever outstanding). Stage-2's B2(0) is prefetched
// during stage-1's last compute + the h-write (long cover).
// One raw s_barrier per kstep. LDS: 17.4 (A/h shared) + 32 (B) = 49.4 KB
// -> 3 blocks/CU (vs old 38.4 KB/3 blocks, occupancy preserved).
// Numerics identical to old version (same rounding points, same k order).
// ---------------------------------------------------------------------------
__global__ __launch_bounds__(256) void gemm_gin(
    const unsigned short* __restrict__ yb,
    const unsigned short* __restrict__ B1h, const unsigned short* __restrict__ B1l,
    const float* __restrict__ b1,
    const unsigned short* __restrict__ B2h, const unsigned short* __restrict__ B2l,
    const float* __restrict__ b2, float* __restrict__ X, int M) {
  constexpr int KSTEPS = 4;   // K=128, BK=32
  constexpr int HSTR = 136;   // 128 + 8 pad
  __shared__ __align__(16) unsigned short AH[64 * HSTR];   // 17.4 KB (A, then h)
  __shared__ __align__(16) unsigned short Bhs[2][4096];    // 16 KB
  __shared__ __align__(16) unsigned short Bls[2][4096];    // 16 KB

  const int tid = threadIdx.x;
  const int wave = tid >> 6;
  const int lane = tid & 63;
  const int m0 = blockIdx.x * 64;

  const int s_row = tid >> 2;
  const int s_grp = tid & 3;          // 32-k group (64 B)
  const int g_row = m0 + s_row;
  const int g_rowc = (g_row < M) ? g_row : (M - 1);
  const unsigned short* ab = yb + (size_t)g_rowc * DH + s_grp * 32;

  const int rgrp = wave & 1;
  const int ch = wave >> 1;
  const int coln = lane & 15;
  const int rown = (lane >> 4) * 4;

  auto issueB = [&](const unsigned short* Bh, const unsigned short* Bl, int ks,
                    int buf) {
    const unsigned short* sh = Bh + (size_t)ks * 4096 + wave * 1024;
    const unsigned short* sl = Bl + (size_t)ks * 4096 + wave * 1024;
    gl_lds16(sh + lane * 8, &Bhs[buf][wave * 1024]);
    gl_lds16(sh + 512 + lane * 8, &Bhs[buf][wave * 1024 + 512]);
    gl_lds16(sl + lane * 8, &Bls[buf][wave * 1024]);
    gl_lds16(sl + 512 + lane * 8, &Bls[buf][wave * 1024 + 512]);
  };

  f32x4 acc[2][4];
#pragma unroll
  for (int r = 0; r < 2; ++r)
#pragma unroll
    for (int c = 0; c < 4; ++c) acc[r][c] = (f32x4){0.f, 0.f, 0.f, 0.f};

  // ---- prologue: full A -> LDS (once), B1(0) in flight ----
  uint4 a0v = *(const uint4*)(ab + 0);
  uint4 a1v = *(const uint4*)(ab + 8);
  uint4 a2v = *(const uint4*)(ab + 16);
  uint4 a3v = *(const uint4*)(ab + 24);
  issueB(B1h, B1l, 0, 0);
  {
    int base = s_row * HSTR + s_grp * 32;
    *(uint4*)&AH[base + 0] = a0v;
    *(uint4*)&AH[base + 8] = a1v;
    *(uint4*)&AH[base + 16] = a2v;
    *(uint4*)&AH[base + 24] = a3v;
  }
  asm volatile("s_waitcnt lgkmcnt(0)" ::: "memory");

  // ================= stage 1: h = relu(y @ W1 + b1) =================
#pragma unroll
  for (int ks = 0; ks < KSTEPS; ++ks) {
    const int cur = ks & 1;
    asm volatile("s_waitcnt vmcnt(0)" ::: "memory");  // B(ks) landed
    __builtin_amdgcn_s_barrier();                      // publish (iter0: + A)
    if (ks + 1 < KSTEPS)
      issueB(B1h, B1l, ks + 1, cur ^ 1);
    else
      issueB(B2h, B2l, 0, cur ^ 1);                    // prefetch stage 2 B(0)

    bf16x8 a0 = *(const bf16x8*)&AH[(rgrp * 32 + (lane & 15)) * HSTR + ks * 32 + (lane >> 4) * 8];
    bf16x8 a1 = *(const bf16x8*)&AH[(rgrp * 32 + 16 + (lane & 15)) * HSTR + ks * 32 + (lane >> 4) * 8];
#pragma unroll
    for (int c = 0; c < 4; ++c) {
      int ct = ch * 4 + c;
      bf16x8 bh = *(const bf16x8*)&Bhs[cur][(ct * 64 + lane) * 8];
      bf16x8 bl = *(const bf16x8*)&Bls[cur][(ct * 64 + lane) * 8];
      acc[0][c] = __builtin_amdgcn_mfma_f32_16x16x32_bf16(a0, bh, acc[0][c], 0, 0, 0);
      acc[0][c] = __builtin_amdgcn_mfma_f32_16x16x32_bf16(a0, bl, acc[0][c], 0, 0, 0);
      acc[1][c] = __builtin_amdgcn_mfma_f32_16x16x32_bf16(a1, bh, acc[1][c], 0, 0, 0);
      acc[1][c] = __builtin_amdgcn_mfma_f32_16x16x32_bf16(a1, bl, acc[1][c], 0, 0, 0);
    }
  }

  // ---- h -> AH (reuse A buffer; all A reads finished before this barrier) ----
  __builtin_amdgcn_s_barrier();
#pragma unroll
  for (int c = 0; c < 4; ++c) {
    int colg = (ch * 4 + c) * 16 + coln;
    float bv = b1[colg];
#pragma unroll
    for (int r = 0; r < 2; ++r) {
#pragma unroll
      for (int reg = 0; reg < 4; ++reg) {
        int lrow = rgrp * 32 + r * 16 + rown + reg;
        float v = fmaxf(acc[r][c][reg] + bv, 0.f);
        AH[lrow * HSTR + colg] = f2bf(v);
      }
      acc[r][c] = (f32x4){0.f, 0.f, 0.f, 0.f};
    }
  }
  asm volatile("s_waitcnt lgkmcnt(0)" ::: "memory");

  // ================= stage 2: X = h @ W2 + b2 =================
#pragma unroll
  for (int ks = 0; ks < KSTEPS; ++ks) {
    const int cur = ks & 1;
    asm volatile("s_waitcnt vmcnt(0)" ::: "memory");  // B2(ks) landed
    __builtin_amdgcn_s_barrier();                      // iter0: publish h too
    if (ks + 1 < KSTEPS) issueB(B2h, B2l, ks + 1, cur ^ 1);

    bf16x8 a0 = *(const bf16x8*)&AH[(rgrp * 32 + (lane & 15)) * HSTR + ks * 32 + (lane >> 4) * 8];
    bf16x8 a1 = *(const bf16x8*)&AH[(rgrp * 32 + 16 + (lane & 15)) * HSTR + ks * 32 + (lane >> 4) * 8];
#pragma unroll
    for (int c = 0; c < 4; ++c) {
      int ct = ch * 4 + c;
      bf16x8 bh = *(const bf16x8*)&Bhs[cur][(ct * 64 + lane) * 8];
      bf16x8 bl = *(const bf16x8*)&Bls[cur][(ct * 64 + lane) * 8];
      acc[0][c] = __builtin_amdgcn_mfma_f32_16x16x32_bf16(a0, bh, acc[0][c], 0, 0, 0);
      acc[0][c] = __builtin_amdgcn_mfma_f32_16x16x32_bf16(a0, bl, acc[0][c], 0, 0, 0);
      acc[1][c] = __builtin_amdgcn_mfma_f32_16x16x32_bf16(a1, bh, acc[1][c], 0, 0, 0);
      acc[1][c] = __builtin_amdgcn_mfma_f32_16x16x32_bf16(a1, bl, acc[1][c], 0, 0, 0);
    }
  }

  // ---- epilogue: X = acc + b2 (no relu) ----
#pragma unroll
  for (int c = 0; c < 4; ++c) {
    int colg = (ch * 4 + c) * 16 + coln;
    float bv = b2[colg];
#pragma unroll
    for (int r = 0; r < 2; ++r) {
#pragma unroll
      for (int reg = 0; reg < 4; ++reg) {
        int row = m0 + rgrp * 32 + r * 16 + rown + reg;
        if (row < M) X[(size_t)row * DH + colg] = acc[r][c][reg] + bv;
      }
    }
  }
}

// ---------------------------------------------------------------------------
// CSR build: degree histogram -> exclusive scan (3 kernels) -> cursor fill.
// ---------------------------------------------------------------------------
__global__ __launch_bounds__(256) void count_deg(const int* __restrict__ eidx,
                                                 int* __restrict__ cnt) {
  int e = blockIdx.x * 256 + threadIdx.x;
  if (e < N_EDGES) atomicAdd(&cnt[eidx[N_EDGES + e]], 1);
}

__global__ __launch_bounds__(256) void scan_block(const int* __restrict__ cnt,
                                                  int* __restrict__ rs,
                                                  int* __restrict__ partials) {
  int t = threadIdx.x;
  int i = blockIdx.x * 256 + t;
  int v = (i < N_NODES) ? cnt[i] : 0;
  __shared__ int s[256];
  s[t] = v;
  __syncthreads();
#pragma unroll
  for (int off = 1; off < 256; off <<= 1) {
    int add = (t >= off) ? s[t - off] : 0;
    __syncthreads();
    s[t] += add;
    __syncthreads();
  }
  if (i < N_NODES) rs[i] = s[t] - v;
  if (t == 255) partials[blockIdx.x] = s[255];
}

__global__ __launch_bounds__(256) void scan_partials(int* __restrict__ partials) {
  int t = threadIdx.x;
  int v = (t < SCAN_BLOCKS) ? partials[t] : 0;
  __shared__ int s[256];
  s[t] = v;
  __syncthreads();
#pragma unroll
  for (int off = 1; off < 256; off <<= 1) {
    int add = (t >= off) ? s[t - off] : 0;
    __syncthreads();
    s[t] += add;
    __syncthreads();
  }
  if (t < SCAN_BLOCKS) partials[t] = s[t] - v;
}

__global__ __launch_bounds__(256) void add_offsets(int* __restrict__ rs,
                                                   const int* __restrict__ partials) {
  int i = blockIdx.x * 256 + threadIdx.x;
  if (i < N_NODES) rs[i] += partials[blockIdx.x];
  if (i == 0) rs[N_NODES] = N_EDGES;
}

__global__ __launch_bounds__(256) void fill_csr(const int* __restrict__ eidx,
                                                const int* __restrict__ rs,
                                                int* __restrict__ cursor,
                                                int* __restrict__ esrc) {
  int e = blockIdx.x * 256 + threadIdx.x;
  if (e >= N_EDGES) return;
  int d = eidx[N_EDGES + e];
  int p = atomicAdd(&cursor[d], 1);
  esrc[rs[d] + p] = eidx[e];
}

// ---------------------------------------------------------------------------
// Aggregation gather (bf16 neighbors): yb[i] = bf16(x[i] + sum_j xb[src_j]).
// Wave per node; lane handles dims (2*lane, 2*lane+1) via one uint load/edge.
// ---------------------------------------------------------------------------
__global__ __launch_bounds__(256) void gin_aggregate_bf16(
    const unsigned short* __restrict__ xb, const float* __restrict__ x,
    const int* __restrict__ rs, const int* __restrict__ esrc,
    unsigned* __restrict__ yb) {
  int node = blockIdx.x * 4 + (threadIdx.x >> 6);
  int lane = threadIdx.x & 63;
  if (node >= N_NODES) return;
  float2 acc = ((const float2*)x)[(size_t)node * 64 + lane];
  const unsigned* xb2 = (const unsigned*)xb;  // 2 bf16 per uint
  int beg = rs[node];
  int end = rs[node + 1];
  int j = beg;
  for (; j + 4 <= end; j += 4) {
    int s0 = esrc[j + 0];
    int s1 = esrc[j + 1];
    int s2 = esrc[j + 2];
    int s3 = esrc[j + 3];
    unsigned v0 = xb2[(size_t)s0 * 64 + lane];
    unsigned v1 = xb2[(size_t)s1 * 64 + lane];
    unsigned v2 = xb2[(size_t)s2 * 64 + lane];
    unsigned v3 = xb2[(size_t)s3 * 64 + lane];
    acc.x += (__uint_as_float(v0 << 16) + __uint_as_float(v1 << 16)) +
             (__uint_as_float(v2 << 16) + __uint_as_float(v3 << 16));
    acc.y += (__uint_as_float(v0 & 0xFFFF0000u) + __uint_as_float(v1 & 0xFFFF0000u)) +
             (__uint_as_float(v2 & 0xFFFF0000u) + __uint_as_float(v3 & 0xFFFF0000u));
  }
  for (; j < end; ++j) {
    unsigned v = xb2[(size_t)esrc[j] * 64 + lane];
    acc.x += __uint_as_float(v << 16);
    acc.y += __uint_as_float(v & 0xFFFF0000u);
  }
  yb[(size_t)node * 64 + lane] =
      (unsigned)f2bf(acc.x) | ((unsigned)f2bf(acc.y) << 16);
}

// ---------------------------------------------------------------------------
// Tail: z[i] = dot(x[i,:], tail_W) + tail_b, plus BN batch-stat partials.
// ---------------------------------------------------------------------------
__global__ __launch_bounds__(256) void tail_bn1(const float* __restrict__ x,
                                                const float* __restrict__ tw,
                                                const float* __restrict__ tb,
                                                float* __restrict__ z,
                                                float* __restrict__ red) {
  const int lane = threadIdx.x & 31;
  const int grp = threadIdx.x >> 5;
  float4 w = *(const float4*)(tw + lane * 4);
  float accS = 0.f, accQ = 0.f;
  for (int node = blockIdx.x * 8 + grp; node < N_NODES; node += gridDim.x * 8) {
    float4 v = *(const float4*)(x + (size_t)node * DH + lane * 4);
    float p = v.x * w.x + v.y * w.y + v.z * w.z + v.w * w.w;
#pragma unroll
    for (int m = 16; m; m >>= 1) p += __shfl_xor(p, m, 32);
    if (lane == 0) {
      float zv = p + tb[0];
      z[node] = zv;
      accS += zv;
      accQ += zv * zv;
    }
  }
  __shared__ float sS[256];
  __shared__ float sQ[256];
  sS[threadIdx.x] = accS;
  sQ[threadIdx.x] = accQ;
  __syncthreads();
  for (int s = 128; s; s >>= 1) {
    if (threadIdx.x < s) {
      sS[threadIdx.x] += sS[threadIdx.x + s];
      sQ[threadIdx.x] += sQ[threadIdx.x + s];
    }
    __syncthreads();
  }
  if (threadIdx.x == 0) {
    atomicAdd(&red[0], sS[0]);
    atomicAdd(&red[1], sQ[0]);
  }
}

__global__ __launch_bounds__(256) void bn2(const float* __restrict__ z,
                                           const float* __restrict__ red,
                                           const float* __restrict__ gamma,
                                           const float* __restrict__ beta,
                                           float* __restrict__ out) {
  int i = blockIdx.x * 256 + threadIdx.x;
  if (i >= N_NODES) return;
  float mu = red[0] * (1.0f / N_NODES);
  float var = red[1] * (1.0f / N_NODES) - mu * mu;
  out[i] = (z[i] - mu) * rsqrtf(var + BN_EPS) * gamma[0] + beta[0];
}

// ---------------------------------------------------------------------------
extern "C" void kernel_launch(void* const* d_in, const int* in_sizes, int n_in,
                              void* d_out, int out_size, void* d_ws, size_t ws_size,
                              hipStream_t stream) {
  const float* feature = (const float*)d_in[0];
  const int* eidx = (const int*)d_in[1];
  const float* head_W = (const float*)d_in[2];
  const float* head_b = (const float*)d_in[3];
  const float* gin_W1 = (const float*)d_in[4];
  const float* gin_b1 = (const float*)d_in[5];
  const float* lin_W1 = (const float*)d_in[6];
  const float* lin_b1 = (const float*)d_in[7];
  const float* gin_W2 = (const float*)d_in[8];
  const float* gin_b2 = (const float*)d_in[9];
  const float* lin_W2 = (const float*)d_in[10];
  const float* lin_b2 = (const float*)d_in[11];
  const float* tail_W = (const float*)d_in[12];
  const float* tail_b = (const float*)d_in[13];
  const float* bn_gamma = (const float*)d_in[14];
  const float* bn_beta = (const float*)d_in[15];

  float* X = (float*)d_ws;                       // N x 128 fp32
  float* z = X + (size_t)N_NODES * DH;           // N
  float* red = z + N_NODES;                      // 2 floats
  int* row_start = (int*)(red + 2);              // N+1
  int* cnt = row_start + (N_NODES + 1);          // N
  int* partials = cnt + N_NODES;                 // 256
  int* esrc = partials + 256;                    // E
  unsigned short* wp =
      (unsigned short*)(((uintptr_t)(esrc + N_EDGES) + 15) & ~(uintptr_t)15);
  unsigned short* hH = wp;            // head hi: 512*128
  unsigned short* hL = hH + 65536;    // head lo
  unsigned short* g1H = hL + 65536;   // 128*128 each below
  unsigned short* g1L = g1H + 16384;
  unsigned short* l1H = g1L + 16384;
  unsigned short* l1L = l1H + 16384;
  unsigned short* g2H = l1L + 16384;
  unsigned short* g2L = g2H + 16384;
  unsigned short* l2H = g2L + 16384;
  unsigned short* l2L = l2H + 16384;
  unsigned short* xb = l2L + 16384;              // bf16 mirror, N x 128
  unsigned short* yb = xb + (size_t)N_NODES * DH;  // agg out bf16, N x 128

  const int gemm_grid = (N_NODES + 63) / 64;     // 782
  const int edge_grid = (N_EDGES + 255) / 256;
  const int agg_grid = (N_NODES + 3) / 4;
  const int cvt_grid = (N_NODES * DH / 4 + 255) / 256;

  // ---- weight pre-split: one fused launch ----
  convert_W5<<<512, 256, 0, stream>>>(head_W, gin_W1, lin_W1, gin_W2, lin_W2,
                                      hH, hL, g1H, g1L, l1H, l1L, g2H, g2L,
                                      l2H, l2L);

  // ---- CSR build (once; reused by both GIN layers) ----
  hipMemsetAsync(cnt, 0, N_NODES * sizeof(int), stream);
  hipMemsetAsync(red, 0, 2 * sizeof(float), stream);
  count_deg<<<edge_grid, 256, 0, stream>>>(eidx, cnt);
  scan_block<<<SCAN_BLOCKS, 256, 0, stream>>>(cnt, row_start, partials);
  scan_partials<<<1, 256, 0, stream>>>(partials);
  add_offsets<<<SCAN_BLOCKS, 256, 0, stream>>>(row_start, partials);
  hipMemsetAsync(cnt, 0, N_NODES * sizeof(int), stream);
  fill_csr<<<edge_grid, 256, 0, stream>>>(eidx, row_start, cnt, esrc);

  // ---- head: X = relu(feature @ head_W + head_b) ----
  gemm_head<<<gemm_grid, 256, 0, stream>>>(feature, hH, hL, head_b, X, N_NODES);

  // ---- layer 1 (fused GIN MLP pair) ----
  to_bf16<<<cvt_grid, 256, 0, stream>>>(X, xb);
  gin_aggregate_bf16<<<agg_grid, 256, 0, stream>>>(xb, X, row_start, esrc,
                                                   (unsigned*)yb);
  gemm_gin<<<gemm_grid, 256, 0, stream>>>(yb, g1H, g1L, gin_b1, l1H, l1L,
                                          lin_b1, X, N_NODES);

  // ---- layer 2 ----
  to_bf16<<<cvt_grid, 256, 0, stream>>>(X, xb);
  gin_aggregate_bf16<<<agg_grid, 256, 0, stream>>>(xb, X, row_start, esrc,
                                                   (unsigned*)yb);
  gemm_gin<<<gemm_grid, 256, 0, stream>>>(yb, g2H, g2L, gin_b2, l2H, l2L,
                                          lin_b2, X, N_NODES);

  // ---- tail + batchnorm ----
  tail_bn1<<<256, 256, 0, stream>>>(X, tail_W, tail_b, z, red);
  bn2<<<(N_NODES + 255) / 256, 256, 0, stream>>>(z, red, bn_gamma, bn_beta, (float*)d_out);
}

// Round 2
// 398.958 us; speedup vs baseline: 1.1004x; 1.1004x over previous
//
#include <hip/hip_runtime.h>

#define N_NODES 50000
#define N_EDGES 600000
#define DH 128
#define BN_EPS 1e-5f
#define SCAN_BLOCKS ((N_NODES + 255) / 256)   // 196

typedef __attribute__((ext_vector_type(8))) short bf16x8;
typedef __attribute__((ext_vector_type(4))) float f32x4;

// round-to-nearest-even fp32 -> bf16 (bit trick, sign-safe)
__device__ inline unsigned short f2bf(float x) {
  unsigned u = __float_as_uint(x);
  return (unsigned short)((u + 0x7FFFu + ((u >> 16) & 1u)) >> 16);
}
__device__ inline float bf2f(unsigned short h) {
  return __uint_as_float(((unsigned)h) << 16);
}

// async global->LDS, 16 B per lane: lane i's data lands at lds_base + i*16.
__device__ inline void gl_lds16(const unsigned short* g, unsigned short* l) {
  __builtin_amdgcn_global_load_lds(
      (const __attribute__((address_space(1))) unsigned int*)g,
      (__attribute__((address_space(3))) unsigned int*)l, 16, 0, 0);
}

// ---------------------------------------------------------------------------
// Fused weight pre-split (one launch). NEW column-slot permutation: output
// col n is placed at MFMA slot invpos(n) so that in the epilogue each lane's
// 4 c-values are CONTIGUOUS output columns (colbase = ch*64 + coln*4 + c).
//   slot ct   = (n>>6)*4 + (n&3)
//   slot coln = (n>>2)&15
// This makes every GEMM epilogue a coalesced float4/uint2 store and lets the
// epilogue emit the bf16 mirror directly (to_bf16 passes eliminated).
// k-mapping unchanged: plane[((kstep32*8 + ctile)*64 + lane)*8 + j],
// k = kstep32*32 + (lane>>4)*8 + j. W split hi/lo (Wh+Wl == W to 2^-17).
// ---------------------------------------------------------------------------
__global__ __launch_bounds__(256) void convert_W5(
    const float* __restrict__ hW, const float* __restrict__ g1,
    const float* __restrict__ l1, const float* __restrict__ g2,
    const float* __restrict__ l2,
    unsigned short* __restrict__ hH, unsigned short* __restrict__ hL,
    unsigned short* __restrict__ g1H, unsigned short* __restrict__ g1L,
    unsigned short* __restrict__ l1H, unsigned short* __restrict__ l1L,
    unsigned short* __restrict__ g2H, unsigned short* __restrict__ g2L,
    unsigned short* __restrict__ l2H, unsigned short* __restrict__ l2L) {
  int b = blockIdx.x;
  const float* W;
  unsigned short *hi, *lo;
  int idx;
  if (b < 256) {
    W = hW; hi = hH; lo = hL;
    idx = b * 256 + threadIdx.x;
  } else {
    int w = (b - 256) >> 6;
    idx = ((b - 256) & 63) * 256 + threadIdx.x;
    W = (w == 0) ? g1 : (w == 1) ? l1 : (w == 2) ? g2 : l2;
    hi = (w == 0) ? g1H : (w == 1) ? l1H : (w == 2) ? g2H : l2H;
    lo = (w == 0) ? g1L : (w == 1) ? l1L : (w == 2) ? g2L : l2L;
  }
  int k = idx >> 7;
  int n = idx & 127;
  float x = W[idx];
  unsigned short h = f2bf(x);
  unsigned short l = f2bf(x - bf2f(h));
  int kstep = k >> 5;
  // ---- column-slot permutation ----
  int ctile = ((n >> 6) << 2) | (n & 3);
  int cs = (n >> 2) & 15;
  int lane = ((k >> 3) & 3) * 16 + cs;
  int j = k & 7;
  size_t off = ((size_t)(kstep * 8 + ctile) * 64 + lane) * 8 + j;
  hi[off] = h;
  lo[off] = l;
}

// ---------------------------------------------------------------------------
// Head GEMM (K=512), R0 proven structure (BK=64, 2 barriers/kstep) + NEW
// coalesced epilogue: float4 X store + fused uint2 bf16 store per (r,reg),
// enabled by the convert_W5 slot permutation. 8 ksteps; LDS ~41 KB ->
// 3 blocks/CU at grid 782.
// ---------------------------------------------------------------------------
__global__ __launch_bounds__(256) void gemm_head(const float* __restrict__ A,
                                                 const unsigned short* __restrict__ Bh,
                                                 const unsigned short* __restrict__ Bl,
                                                 const float* __restrict__ bias,
                                                 float* __restrict__ C,
                                                 unsigned short* __restrict__ xb_out,
                                                 int M) {
  constexpr int K = 512;
  constexpr int KSTEPS = K / 64;
  constexpr int ASTR = 72;  // 64 k + 8 pad (2-way bank alias = free)
  __shared__ __align__(16) unsigned short Ah[64 * ASTR];   // 9.2 KB
  __shared__ __align__(16) unsigned short Bhs[2][4096];    // 16 KB
  __shared__ __align__(16) unsigned short Bls[2][4096];    // 16 KB

  const int tid = threadIdx.x;
  const int wave = tid >> 6;
  const int lane = tid & 63;
  const int m0 = blockIdx.x * 64;

  // A staging: thread owns row tid>>2 (0..63), 16-elem group tid&3
  const int s_row = tid >> 2;
  const int s_grp = tid & 3;
  const int g_row = m0 + s_row;
  const int g_rowc = (g_row < M) ? g_row : (M - 1);
  const float* af = A + (size_t)g_rowc * K + s_grp * 16;

  const int rgrp = wave & 1;  // 32-row group
  const int ch = wave >> 1;   // 64-col half

  f32x4 acc[2][4];
#pragma unroll
  for (int r = 0; r < 2; ++r)
#pragma unroll
    for (int c = 0; c < 4; ++c) acc[r][c] = (f32x4){0.f, 0.f, 0.f, 0.f};

  for (int ks = 0; ks < KSTEPS; ++ks) {
    // ---- stage A (64 rows x 64 k fp32 -> bf16) ----
    {
      float4 f0 = *(const float4*)(af + ks * 64);
      float4 f1 = *(const float4*)(af + ks * 64 + 4);
      float4 f2 = *(const float4*)(af + ks * 64 + 8);
      float4 f3 = *(const float4*)(af + ks * 64 + 12);
      ushort4 h0, h1, h2, h3;
      h0.x = f2bf(f0.x); h0.y = f2bf(f0.y); h0.z = f2bf(f0.z); h0.w = f2bf(f0.w);
      h1.x = f2bf(f1.x); h1.y = f2bf(f1.y); h1.z = f2bf(f1.z); h1.w = f2bf(f1.w);
      h2.x = f2bf(f2.x); h2.y = f2bf(f2.y); h2.z = f2bf(f2.z); h2.w = f2bf(f2.w);
      h3.x = f2bf(f3.x); h3.y = f2bf(f3.y); h3.z = f2bf(f3.z); h3.w = f2bf(f3.w);
      int base = s_row * ASTR + s_grp * 16;
      *(ushort4*)&Ah[base + 0] = h0;
      *(ushort4*)&Ah[base + 4] = h1;
      *(ushort4*)&Ah[base + 8] = h2;
      *(ushort4*)&Ah[base + 12] = h3;
    }
    // ---- stage B: two 32-k sub-steps, 8 KB per plane each ----
#pragma unroll
    for (int s = 0; s < 2; ++s) {
      const unsigned short* sh = Bh + (size_t)(2 * ks + s) * 4096 + wave * 1024;
      const unsigned short* sl = Bl + (size_t)(2 * ks + s) * 4096 + wave * 1024;
      gl_lds16(sh + lane * 8, &Bhs[s][wave * 1024]);
      gl_lds16(sh + 512 + lane * 8, &Bhs[s][wave * 1024 + 512]);
      gl_lds16(sl + lane * 8, &Bls[s][wave * 1024]);
      gl_lds16(sl + 512 + lane * 8, &Bls[s][wave * 1024 + 512]);
    }
    __syncthreads();

    // ---- compute: 2 k-chunks x 4 c-tiles x (hi+lo) x 2 row-frags ----
#pragma unroll
    for (int s = 0; s < 2; ++s) {
      bf16x8 a0 = *(const bf16x8*)&Ah[(rgrp * 32 + (lane & 15)) * ASTR + s * 32 + (lane >> 4) * 8];
      bf16x8 a1 = *(const bf16x8*)&Ah[(rgrp * 32 + 16 + (lane & 15)) * ASTR + s * 32 + (lane >> 4) * 8];
#pragma unroll
      for (int c = 0; c < 4; ++c) {
        int ct = ch * 4 + c;
        bf16x8 bh = *(const bf16x8*)&Bhs[s][(ct * 64 + lane) * 8];
        bf16x8 bl = *(const bf16x8*)&Bls[s][(ct * 64 + lane) * 8];
        acc[0][c] = __builtin_amdgcn_mfma_f32_16x16x32_bf16(a0, bh, acc[0][c], 0, 0, 0);
        acc[0][c] = __builtin_amdgcn_mfma_f32_16x16x32_bf16(a0, bl, acc[0][c], 0, 0, 0);
        acc[1][c] = __builtin_amdgcn_mfma_f32_16x16x32_bf16(a1, bh, acc[1][c], 0, 0, 0);
        acc[1][c] = __builtin_amdgcn_mfma_f32_16x16x32_bf16(a1, bl, acc[1][c], 0, 0, 0);
      }
    }
    __syncthreads();
  }

  // ---- epilogue: slot c holds output col colbase+c (slot permutation) ----
  const int coln = lane & 15;
  const int rown = (lane >> 4) * 4;
  const int colbase = ch * 64 + coln * 4;
  const float4 bv = *(const float4*)(bias + colbase);
#pragma unroll
  for (int r = 0; r < 2; ++r) {
#pragma unroll
    for (int reg = 0; reg < 4; ++reg) {
      int row = m0 + rgrp * 32 + r * 16 + rown + reg;
      if (row < M) {
        float4 v;
        v.x = fmaxf(acc[r][0][reg] + bv.x, 0.f);
        v.y = fmaxf(acc[r][1][reg] + bv.y, 0.f);
        v.z = fmaxf(acc[r][2][reg] + bv.z, 0.f);
        v.w = fmaxf(acc[r][3][reg] + bv.w, 0.f);
        *(float4*)&C[(size_t)row * DH + colbase] = v;
        ushort4 hb;
        hb.x = f2bf(v.x); hb.y = f2bf(v.y); hb.z = f2bf(v.z); hb.w = f2bf(v.w);
        *(ushort4*)&xb_out[(size_t)row * DH + colbase] = hb;
      }
    }
  }
}

// ---------------------------------------------------------------------------
// Fused GIN MLP pair (R0 proven structure) + NEW coalesced epilogue with
// optional fused bf16 mirror (xb_out != nullptr for layer 1 only).
// Stage 1: A = yb (bf16), B = W1 planes -> h = relu(acc+b1) -> LDS.
// Stage 2: A-frags ds_read from h, B = W2 planes.
// LDS: 5 + 16 + 17.4 = 38.4 KB -> 3 blocks/CU at grid 782.
// ---------------------------------------------------------------------------
__global__ __launch_bounds__(256) void gemm_gin(
    const unsigned short* __restrict__ yb,
    const unsigned short* __restrict__ B1h, const unsigned short* __restrict__ B1l,
    const float* __restrict__ b1,
    const unsigned short* __restrict__ B2h, const unsigned short* __restrict__ B2l,
    const float* __restrict__ b2, float* __restrict__ X,
    unsigned short* __restrict__ xb_out, int M) {
  constexpr int K = 128;
  constexpr int KSTEPS = K / 32;
  constexpr int ASTR = 40;
  constexpr int HSTR = 136;  // 128 + 8 pad
  __shared__ __align__(16) unsigned short Ah[64 * ASTR];   // 5 KB
  __shared__ __align__(16) unsigned short Bhs[4096];       // 8 KB
  __shared__ __align__(16) unsigned short Bls[4096];       // 8 KB
  __shared__ __align__(16) unsigned short Hb[64 * HSTR];   // 17.4 KB

  const int tid = threadIdx.x;
  const int wave = tid >> 6;
  const int lane = tid & 63;
  const int m0 = blockIdx.x * 64;

  const int s_row = tid >> 2;
  const int s_oct = tid & 3;
  const int g_row = m0 + s_row;
  const int g_rowc = (g_row < M) ? g_row : (M - 1);
  const unsigned short* ab = yb + (size_t)g_rowc * K + s_oct * 8;

  const int rgrp = wave & 1;
  const int ch = wave >> 1;
  const int coln = lane & 15;
  const int rown = (lane >> 4) * 4;
  const int colbase = ch * 64 + coln * 4;

  auto issueB = [&](const unsigned short* Bh, const unsigned short* Bl, int ks) {
    const unsigned short* sh = Bh + (size_t)ks * 4096 + wave * 1024;
    const unsigned short* sl = Bl + (size_t)ks * 4096 + wave * 1024;
    gl_lds16(sh + lane * 8, &Bhs[wave * 1024]);
    gl_lds16(sh + 512 + lane * 8, &Bhs[wave * 1024 + 512]);
    gl_lds16(sl + lane * 8, &Bls[wave * 1024]);
    gl_lds16(sl + 512 + lane * 8, &Bls[wave * 1024 + 512]);
  };

  f32x4 acc[2][4];
#pragma unroll
  for (int r = 0; r < 2; ++r)
#pragma unroll
    for (int c = 0; c < 4; ++c) acc[r][c] = (f32x4){0.f, 0.f, 0.f, 0.f};

  // ================= stage 1: h = relu(y @ W1 + b1) =================
  for (int ks = 0; ks < KSTEPS; ++ks) {
    *(uint4*)&Ah[s_row * ASTR + s_oct * 8] = *(const uint4*)(ab + ks * 32);
    issueB(B1h, B1l, ks);
    __syncthreads();
    bf16x8 a0 = *(const bf16x8*)&Ah[(rgrp * 32 + (lane & 15)) * ASTR + (lane >> 4) * 8];
    bf16x8 a1 = *(const bf16x8*)&Ah[(rgrp * 32 + 16 + (lane & 15)) * ASTR + (lane >> 4) * 8];
#pragma unroll
    for (int c = 0; c < 4; ++c) {
      int ct = ch * 4 + c;
      bf16x8 bh = *(const bf16x8*)&Bhs[(ct * 64 + lane) * 8];
      bf16x8 bl = *(const bf16x8*)&Bls[(ct * 64 + lane) * 8];
      acc[0][c] = __builtin_amdgcn_mfma_f32_16x16x32_bf16(a0, bh, acc[0][c], 0, 0, 0);
      acc[0][c] = __builtin_amdgcn_mfma_f32_16x16x32_bf16(a0, bl, acc[0][c], 0, 0, 0);
      acc[1][c] = __builtin_amdgcn_mfma_f32_16x16x32_bf16(a1, bh, acc[1][c], 0, 0, 0);
      acc[1][c] = __builtin_amdgcn_mfma_f32_16x16x32_bf16(a1, bl, acc[1][c], 0, 0, 0);
    }
    __syncthreads();
  }

  // ---- h -> LDS bf16: slot c holds hidden col colbase+c (standard layout) ----
  {
    const float4 bv = *(const float4*)(b1 + colbase);
#pragma unroll
    for (int r = 0; r < 2; ++r) {
#pragma unroll
      for (int reg = 0; reg < 4; ++reg) {
        int lrow = rgrp * 32 + r * 16 + rown + reg;
        ushort4 hb;
        hb.x = f2bf(fmaxf(acc[r][0][reg] + bv.x, 0.f));
        hb.y = f2bf(fmaxf(acc[r][1][reg] + bv.y, 0.f));
        hb.z = f2bf(fmaxf(acc[r][2][reg] + bv.z, 0.f));
        hb.w = f2bf(fmaxf(acc[r][3][reg] + bv.w, 0.f));
        *(ushort4*)&Hb[lrow * HSTR + colbase] = hb;
      }
    }
#pragma unroll
    for (int r = 0; r < 2; ++r)
#pragma unroll
      for (int c = 0; c < 4; ++c) acc[r][c] = (f32x4){0.f, 0.f, 0.f, 0.f};
  }

  // ================= stage 2: X = h @ W2 + b2 =================
  for (int ks = 0; ks < KSTEPS; ++ks) {
    issueB(B2h, B2l, ks);
    __syncthreads();  // first iter: also publishes Hb to all waves
    bf16x8 a0 = *(const bf16x8*)&Hb[(rgrp * 32 + (lane & 15)) * HSTR + ks * 32 + (lane >> 4) * 8];
    bf16x8 a1 = *(const bf16x8*)&Hb[(rgrp * 32 + 16 + (lane & 15)) * HSTR + ks * 32 + (lane >> 4) * 8];
#pragma unroll
    for (int c = 0; c < 4; ++c) {
      int ct = ch * 4 + c;
      bf16x8 bh = *(const bf16x8*)&Bhs[(ct * 64 + lane) * 8];
      bf16x8 bl = *(const bf16x8*)&Bls[(ct * 64 + lane) * 8];
      acc[0][c] = __builtin_amdgcn_mfma_f32_16x16x32_bf16(a0, bh, acc[0][c], 0, 0, 0);
      acc[0][c] = __builtin_amdgcn_mfma_f32_16x16x32_bf16(a0, bl, acc[0][c], 0, 0, 0);
      acc[1][c] = __builtin_amdgcn_mfma_f32_16x16x32_bf16(a1, bh, acc[1][c], 0, 0, 0);
      acc[1][c] = __builtin_amdgcn_mfma_f32_16x16x32_bf16(a1, bl, acc[1][c], 0, 0, 0);
    }
    __syncthreads();
  }

  // ---- epilogue: X = acc + b2 (no relu), optional fused bf16 mirror ----
  {
    const float4 bv = *(const float4*)(b2 + colbase);
#pragma unroll
    for (int r = 0; r < 2; ++r) {
#pragma unroll
      for (int reg = 0; reg < 4; ++reg) {
        int row = m0 + rgrp * 32 + r * 16 + rown + reg;
        if (row < M) {
          float4 v;
          v.x = acc[r][0][reg] + bv.x;
          v.y = acc[r][1][reg] + bv.y;
          v.z = acc[r][2][reg] + bv.z;
          v.w = acc[r][3][reg] + bv.w;
          *(float4*)&X[(size_t)row * DH + colbase] = v;
          if (xb_out) {
            ushort4 hb;
            hb.x = f2bf(v.x); hb.y = f2bf(v.y); hb.z = f2bf(v.z); hb.w = f2bf(v.w);
            *(ushort4*)&xb_out[(size_t)row * DH + colbase] = hb;
          }
        }
      }
    }
  }
}

// ---------------------------------------------------------------------------
// CSR build: degree histogram -> exclusive scan (3 kernels) -> cursor fill.
// ---------------------------------------------------------------------------
__global__ __launch_bounds__(256) void count_deg(const int* __restrict__ eidx,
                                                 int* __restrict__ cnt) {
  int e = blockIdx.x * 256 + threadIdx.x;
  if (e < N_EDGES) atomicAdd(&cnt[eidx[N_EDGES + e]], 1);
}

__global__ __launch_bounds__(256) void scan_block(const int* __restrict__ cnt,
                                                  int* __restrict__ rs,
                                                  int* __restrict__ partials) {
  int t = threadIdx.x;
  int i = blockIdx.x * 256 + t;
  int v = (i < N_NODES) ? cnt[i] : 0;
  __shared__ int s[256];
  s[t] = v;
  __syncthreads();
#pragma unroll
  for (int off = 1; off < 256; off <<= 1) {
    int add = (t >= off) ? s[t - off] : 0;
    __syncthreads();
    s[t] += add;
    __syncthreads();
  }
  if (i < N_NODES) rs[i] = s[t] - v;
  if (t == 255) partials[blockIdx.x] = s[255];
}

__global__ __launch_bounds__(256) void scan_partials(int* __restrict__ partials) {
  int t = threadIdx.x;
  int v = (t < SCAN_BLOCKS) ? partials[t] : 0;
  __shared__ int s[256];
  s[t] = v;
  __syncthreads();
#pragma unroll
  for (int off = 1; off < 256; off <<= 1) {
    int add = (t >= off) ? s[t - off] : 0;
    __syncthreads();
    s[t] += add;
    __syncthreads();
  }
  if (t < SCAN_BLOCKS) partials[t] = s[t] - v;
}

__global__ __launch_bounds__(256) void add_offsets(int* __restrict__ rs,
                                                   const int* __restrict__ partials) {
  int i = blockIdx.x * 256 + threadIdx.x;
  if (i < N_NODES) rs[i] += partials[blockIdx.x];
  if (i == 0) rs[N_NODES] = N_EDGES;
}

__global__ __launch_bounds__(256) void fill_csr(const int* __restrict__ eidx,
                                                const int* __restrict__ rs,
                                                int* __restrict__ cursor,
                                                int* __restrict__ esrc) {
  int e = blockIdx.x * 256 + threadIdx.x;
  if (e >= N_EDGES) return;
  int d = eidx[N_EDGES + e];
  int p = atomicAdd(&cursor[d], 1);
  esrc[rs[d] + p] = eidx[e];
}

// ---------------------------------------------------------------------------
// Aggregation gather (bf16 neighbors): yb[i] = bf16(x[i] + sum_j xb[src_j]).
// Wave per node; lane handles dims (2*lane, 2*lane+1) via one uint load/edge.
// Unrolled 8-wide for deeper MLP (mean degree = 12).
// ---------------------------------------------------------------------------
__global__ __launch_bounds__(256) void gin_aggregate_bf16(
    const unsigned short* __restrict__ xb, const float* __restrict__ x,
    const int* __restrict__ rs, const int* __restrict__ esrc,
    unsigned* __restrict__ yb) {
  int node = blockIdx.x * 4 + (threadIdx.x >> 6);
  int lane = threadIdx.x & 63;
  if (node >= N_NODES) return;
  float2 acc = ((const float2*)x)[(size_t)node * 64 + lane];
  const unsigned* xb2 = (const unsigned*)xb;  // 2 bf16 per uint
  int beg = rs[node];
  int end = rs[node + 1];
  int j = beg;
  for (; j + 8 <= end; j += 8) {
    int s0 = esrc[j + 0];
    int s1 = esrc[j + 1];
    int s2 = esrc[j + 2];
    int s3 = esrc[j + 3];
    int s4 = esrc[j + 4];
    int s5 = esrc[j + 5];
    int s6 = esrc[j + 6];
    int s7 = esrc[j + 7];
    unsigned v0 = xb2[(size_t)s0 * 64 + lane];
    unsigned v1 = xb2[(size_t)s1 * 64 + lane];
    unsigned v2 = xb2[(size_t)s2 * 64 + lane];
    unsigned v3 = xb2[(size_t)s3 * 64 + lane];
    unsigned v4 = xb2[(size_t)s4 * 64 + lane];
    unsigned v5 = xb2[(size_t)s5 * 64 + lane];
    unsigned v6 = xb2[(size_t)s6 * 64 + lane];
    unsigned v7 = xb2[(size_t)s7 * 64 + lane];
    acc.x += ((__uint_as_float(v0 << 16) + __uint_as_float(v1 << 16)) +
              (__uint_as_float(v2 << 16) + __uint_as_float(v3 << 16))) +
             ((__uint_as_float(v4 << 16) + __uint_as_float(v5 << 16)) +
              (__uint_as_float(v6 << 16) + __uint_as_float(v7 << 16)));
    acc.y += ((__uint_as_float(v0 & 0xFFFF0000u) + __uint_as_float(v1 & 0xFFFF0000u)) +
              (__uint_as_float(v2 & 0xFFFF0000u) + __uint_as_float(v3 & 0xFFFF0000u))) +
             ((__uint_as_float(v4 & 0xFFFF0000u) + __uint_as_float(v5 & 0xFFFF0000u)) +
              (__uint_as_float(v6 & 0xFFFF0000u) + __uint_as_float(v7 & 0xFFFF0000u)));
  }
  for (; j + 4 <= end; j += 4) {
    int s0 = esrc[j + 0];
    int s1 = esrc[j + 1];
    int s2 = esrc[j + 2];
    int s3 = esrc[j + 3];
    unsigned v0 = xb2[(size_t)s0 * 64 + lane];
    unsigned v1 = xb2[(size_t)s1 * 64 + lane];
    unsigned v2 = xb2[(size_t)s2 * 64 + lane];
    unsigned v3 = xb2[(size_t)s3 * 64 + lane];
    acc.x += (__uint_as_float(v0 << 16) + __uint_as_float(v1 << 16)) +
             (__uint_as_float(v2 << 16) + __uint_as_float(v3 << 16));
    acc.y += (__uint_as_float(v0 & 0xFFFF0000u) + __uint_as_float(v1 & 0xFFFF0000u)) +
             (__uint_as_float(v2 & 0xFFFF0000u) + __uint_as_float(v3 & 0xFFFF0000u));
  }
  for (; j < end; ++j) {
    unsigned v = xb2[(size_t)esrc[j] * 64 + lane];
    acc.x += __uint_as_float(v << 16);
    acc.y += __uint_as_float(v & 0xFFFF0000u);
  }
  yb[(size_t)node * 64 + lane] =
      (unsigned)f2bf(acc.x) | ((unsigned)f2bf(acc.y) << 16);
}

// ---------------------------------------------------------------------------
// Tail: z[i] = dot(x[i,:], tail_W) + tail_b, plus BN batch-stat partials.
// ---------------------------------------------------------------------------
__global__ __launch_bounds__(256) void tail_bn1(const float* __restrict__ x,
                                                const float* __restrict__ tw,
                                                const float* __restrict__ tb,
                                                float* __restrict__ z,
                                                float* __restrict__ red) {
  const int lane = threadIdx.x & 31;
  const int grp = threadIdx.x >> 5;
  float4 w = *(const float4*)(tw + lane * 4);
  float accS = 0.f, accQ = 0.f;
  for (int node = blockIdx.x * 8 + grp; node < N_NODES; node += gridDim.x * 8) {
    float4 v = *(const float4*)(x + (size_t)node * DH + lane * 4);
    float p = v.x * w.x + v.y * w.y + v.z * w.z + v.w * w.w;
#pragma unroll
    for (int m = 16; m; m >>= 1) p += __shfl_xor(p, m, 32);
    if (lane == 0) {
      float zv = p + tb[0];
      z[node] = zv;
      accS += zv;
      accQ += zv * zv;
    }
  }
  __shared__ float sS[256];
  __shared__ float sQ[256];
  sS[threadIdx.x] = accS;
  sQ[threadIdx.x] = accQ;
  __syncthreads();
  for (int s = 128; s; s >>= 1) {
    if (threadIdx.x < s) {
      sS[threadIdx.x] += sS[threadIdx.x + s];
      sQ[threadIdx.x] += sQ[threadIdx.x + s];
    }
    __syncthreads();
  }
  if (threadIdx.x == 0) {
    atomicAdd(&red[0], sS[0]);
    atomicAdd(&red[1], sQ[0]);
  }
}

__global__ __launch_bounds__(256) void bn2(const float* __restrict__ z,
                                           const float* __restrict__ red,
                                           const float* __restrict__ gamma,
                                           const float* __restrict__ beta,
                                           float* __restrict__ out) {
  int i = blockIdx.x * 256 + threadIdx.x;
  if (i >= N_NODES) return;
  float mu = red[0] * (1.0f / N_NODES);
  float var = red[1] * (1.0f / N_NODES) - mu * mu;
  out[i] = (z[i] - mu) * rsqrtf(var + BN_EPS) * gamma[0] + beta[0];
}

// ---------------------------------------------------------------------------
extern "C" void kernel_launch(void* const* d_in, const int* in_sizes, int n_in,
                              void* d_out, int out_size, void* d_ws, size_t ws_size,
                              hipStream_t stream) {
  const float* feature = (const float*)d_in[0];
  const int* eidx = (const int*)d_in[1];
  const float* head_W = (const float*)d_in[2];
  const float* head_b = (const float*)d_in[3];
  const float* gin_W1 = (const float*)d_in[4];
  const float* gin_b1 = (const float*)d_in[5];
  const float* lin_W1 = (const float*)d_in[6];
  const float* lin_b1 = (const float*)d_in[7];
  const float* gin_W2 = (const float*)d_in[8];
  const float* gin_b2 = (const float*)d_in[9];
  const float* lin_W2 = (const float*)d_in[10];
  const float* lin_b2 = (const float*)d_in[11];
  const float* tail_W = (const float*)d_in[12];
  const float* tail_b = (const float*)d_in[13];
  const float* bn_gamma = (const float*)d_in[14];
  const float* bn_beta = (const float*)d_in[15];

  float* X = (float*)d_ws;                       // N x 128 fp32
  float* z = X + (size_t)N_NODES * DH;           // N
  float* red = z + N_NODES;                      // 2 floats
  int* row_start = (int*)(red + 2);              // N+1
  int* cnt = row_start + (N_NODES + 1);          // N
  int* partials = cnt + N_NODES;                 // 256
  int* esrc = partials + 256;                    // E
  unsigned short* wp =
      (unsigned short*)(((uintptr_t)(esrc + N_EDGES) + 15) & ~(uintptr_t)15);
  unsigned short* hH = wp;            // head hi: 512*128
  unsigned short* hL = hH + 65536;    // head lo
  unsigned short* g1H = hL + 65536;   // 128*128 each below
  unsigned short* g1L = g1H + 16384;
  unsigned short* l1H = g1L + 16384;
  unsigned short* l1L = l1H + 16384;
  unsigned short* g2H = l1L + 16384;
  unsigned short* g2L = g2H + 16384;
  unsigned short* l2H = g2L + 16384;
  unsigned short* l2L = l2H + 16384;
  unsigned short* xb = l2L + 16384;              // bf16 mirror, N x 128
  unsigned short* yb = xb + (size_t)N_NODES * DH;  // agg out bf16, N x 128

  const int gemm_grid = (N_NODES + 63) / 64;     // 782
  const int edge_grid = (N_EDGES + 255) / 256;
  const int agg_grid = (N_NODES + 3) / 4;

  // ---- weight pre-split: one fused launch ----
  convert_W5<<<512, 256, 0, stream>>>(head_W, gin_W1, lin_W1, gin_W2, lin_W2,
                                      hH, hL, g1H, g1L, l1H, l1L, g2H, g2L,
                                      l2H, l2L);

  // ---- CSR build (once; reused by both GIN layers) ----
  hipMemsetAsync(cnt, 0, N_NODES * sizeof(int), stream);
  hipMemsetAsync(red, 0, 2 * sizeof(float), stream);
  count_deg<<<edge_grid, 256, 0, stream>>>(eidx, cnt);
  scan_block<<<SCAN_BLOCKS, 256, 0, stream>>>(cnt, row_start, partials);
  scan_partials<<<1, 256, 0, stream>>>(partials);
  add_offsets<<<SCAN_BLOCKS, 256, 0, stream>>>(row_start, partials);
  hipMemsetAsync(cnt, 0, N_NODES * sizeof(int), stream);
  fill_csr<<<edge_grid, 256, 0, stream>>>(eidx, row_start, cnt, esrc);

  // ---- head: X = relu(feature @ head_W + head_b), fused bf16 mirror ----
  gemm_head<<<gemm_grid, 256, 0, stream>>>(feature, hH, hL, head_b, X, xb,
                                           N_NODES);

  // ---- layer 1 (fused GIN MLP pair; emits next bf16 mirror) ----
  gin_aggregate_bf16<<<agg_grid, 256, 0, stream>>>(xb, X, row_start, esrc,
                                                   (unsigned*)yb);
  gemm_gin<<<gemm_grid, 256, 0, stream>>>(yb, g1H, g1L, gin_b1, l1H, l1L,
                                          lin_b1, X, xb, N_NODES);

  // ---- layer 2 (no bf16 mirror needed after) ----
  gin_aggregate_bf16<<<agg_grid, 256, 0, stream>>>(xb, X, row_start, esrc,
                                                   (unsigned*)yb);
  gemm_gin<<<gemm_grid, 256, 0, stream>>>(yb, g2H, g2L, gin_b2, l2H, l2L,
                                          lin_b2, X, nullptr, N_NODES);

  // ---- tail + batchnorm ----
  tail_bn1<<<256, 256, 0, stream>>>(X, tail_W, tail_b, z, red);
  bn2<<<(N_NODES + 255) / 256, 256, 0, stream>>>(z, red, bn_gamma, bn_beta, (float*)d_out);
}